// Round 10
// baseline (83.214 us; speedup 1.0000x reference)
//
#include <hip/hip_runtime.h>

// ChannelAttention on MI355X (gfx950) — R9: fully-fused split-bf16 MFMA
// B=128, HW=256, C=1024, S=32, EMB=256, IDF=256(==HW)
//
// out[b,p,c] = sum_s we[b,s,p] * softmax_s( sum_p' wc[b,p',c] * we[b,s,p'] )
// attn[b,c,s] = softmax probabilities
// d_out: out (128*256*1024 f32) then attn (128*1024*32 f32); d_ws unused.
//
// R9 = R8 + fusion: each block recomputes weT[b] (emb x K, split-bf16 MFMA,
// M=s/N=p so emb loads contiguous) into LDS in BOTH layouts:
//   wHT/wLT[s][p] (transposed, hi+lo) -> phase-A B-frags = 1x ds_read_b128
//     (replaces R8's 256 scalar ds_read_u16 per wave)
//   wHp[p][s] (hi only)               -> phase-B A-frags
// P stored hi-only (error budget: +~1.6e-2 abs, threshold 9.8e-2).
// Removes we_proj kernel + 8 MB weT HBM round trip. wc prefetch issued
// before projection so HBM latency hides under projection MFMA.
// mfma_f32_16x16x32_bf16 layouts (R8-verified on HW):
//   A[M][K]: row=l&15, k=(l>>4)*8+i ; B[K][N]: col=l&15, same k
//   C/D: col=l&15, row=(l>>4)*4+reg

typedef float  f32x4  __attribute__((ext_vector_type(4)));
typedef short  bf16x8 __attribute__((ext_vector_type(8)));

namespace {
constexpr int kB = 128, kHW = 256, kC = 1024, kS = 32, kE = 256;
constexpr int TP = kHW + 8;  // 264 u16 = 528B row stride (16B-mult, 2-way banks)
constexpr int WR = kS + 8;   // 40 u16 = 80B row stride (16B-mult)
}

__device__ inline ushort f2bf(float x) {             // f32 -> bf16 RNE
  unsigned u = __float_as_uint(x);
  u += 0x7fffu + ((u >> 16) & 1u);
  return (ushort)(u >> 16);
}
__device__ inline float bf2f(ushort h) { return __uint_as_float(((unsigned)h) << 16); }

#define MFMA16(A, Bf, Cv) __builtin_amdgcn_mfma_f32_16x16x32_bf16((A), (Bf), (Cv), 0, 0, 0)

// grid (4,128), 256 thr = 4 waves; block: one b, 256 channels; wave: 64 c's
// (phase A/softmax) and 64 p's (projection).
__global__ __launch_bounds__(256, 2) void fused_attn_kernel(
    const float* __restrict__ wc, const float* __restrict__ emb,
    const float* __restrict__ Km, const float* __restrict__ bias,
    float* __restrict__ out, float* __restrict__ attn_out) {
  const int b    = blockIdx.y;
  const int cb   = blockIdx.x * 256;
  const int tid  = threadIdx.x;
  const int wave = tid >> 6, lane = tid & 63;
  const int lr   = lane & 15, lg = lane >> 4;

  __shared__ ushort wHT[kS][TP];    // weT^T hi: [s][p]   16.9 KB
  __shared__ ushort wLT[kS][TP];    // weT^T lo: [s][p]   16.9 KB
  __shared__ ushort wHp[kHW][WR];   // weT hi:   [p][s]   20.5 KB
  __shared__ ushort pHl[kHW][WR];   // P hi:     [c][s]   20.5 KB   -> 74.7 KB

  const float* wcb = wc + (size_t)b * kHW * kC;
  const int c0 = cb + wave * 64;

  // ---- issue first wc prefetch now; latency hides under projection ----
  float avC[8], avN[8];
#pragma unroll
  for (int i = 0; i < 8; ++i)
    avC[i] = wcb[(size_t)(lg * 8 + i) * kC + c0 + lr];

  // ---- projection: weT[s][p] = sum_e emb[b][s][e]*K[e][p] (+bias later) ----
  // M=s (2 tiles), N=p (wave owns 4 tiles = 64 p), K-dim=e (8 k-tiles)
  {
    const float* embb = emb + (size_t)b * kS * kE;
    f32x4 pcc[2][4];
#pragma unroll
    for (int m = 0; m < 2; ++m)
#pragma unroll
      for (int n = 0; n < 4; ++n) pcc[m][n] = (f32x4){0.f, 0.f, 0.f, 0.f};

#pragma unroll 1
    for (int kt = 0; kt < 8; ++kt) {
      bf16x8 eah[2], eal[2];
#pragma unroll
      for (int m = 0; m < 2; ++m) {
        const float* ep = embb + (size_t)(m * 16 + lr) * kE + kt * 32 + lg * 8;
        const float4 v0 = *(const float4*)ep;
        const float4 v1 = *(const float4*)(ep + 4);
        const float ev[8] = {v0.x, v0.y, v0.z, v0.w, v1.x, v1.y, v1.z, v1.w};
#pragma unroll
        for (int i = 0; i < 8; ++i) {
          const ushort h = f2bf(ev[i]);
          eah[m][i] = (short)h;
          eal[m][i] = (short)f2bf(ev[i] - bf2f(h));
        }
      }
#pragma unroll
      for (int n = 0; n < 4; ++n) {
        const int pg = wave * 64 + n * 16 + lr;
        bf16x8 kh, kl;
#pragma unroll
        for (int i = 0; i < 8; ++i) {
          const float kv = Km[(size_t)(kt * 32 + lg * 8 + i) * kHW + pg];
          const ushort h = f2bf(kv);
          kh[i] = (short)h;
          kl[i] = (short)f2bf(kv - bf2f(h));
        }
#pragma unroll
        for (int m = 0; m < 2; ++m) {
          pcc[m][n] = MFMA16(eah[m], kh, pcc[m][n]);
          pcc[m][n] = MFMA16(eah[m], kl, pcc[m][n]);
          pcc[m][n] = MFMA16(eal[m], kh, pcc[m][n]);
        }
      }
    }
    // bias + split + write both LDS layouts
#pragma unroll
    for (int n = 0; n < 4; ++n) {
      const int pg = wave * 64 + n * 16 + lr;
      const float bv = bias[pg];
#pragma unroll
      for (int m = 0; m < 2; ++m)
#pragma unroll
        for (int j = 0; j < 4; ++j) {
          const float x = pcc[m][n][j] + bv;
          const ushort h = f2bf(x);
          const ushort l = f2bf(x - bf2f(h));
          const int s = m * 16 + lg * 4 + j;
          wHT[s][pg] = h;
          wLT[s][pg] = l;
          wHp[pg][s] = h;
        }
    }
  }
  __syncthreads();

  // ---- Phase A: D[c][s], A=wc^T (global, split in-reg), B=weT^T (LDS b128)
  f32x4 acc[4][2];
#pragma unroll
  for (int m = 0; m < 4; ++m)
#pragma unroll
    for (int n = 0; n < 2; ++n) acc[m][n] = (f32x4){0.f, 0.f, 0.f, 0.f};

#pragma unroll 1
  for (int kt = 0; kt < 8; ++kt) {
    bf16x8 bh[2], bl[2];
#pragma unroll
    for (int n = 0; n < 2; ++n) {
      bh[n] = *(const bf16x8*)&wHT[n * 16 + lr][kt * 32 + lg * 8];
      bl[n] = *(const bf16x8*)&wLT[n * 16 + lr][kt * 32 + lg * 8];
    }
#pragma unroll
    for (int m = 0; m < 4; ++m) {
      const int mn  = (m + 1) & 3;
      const int ktn = (m == 3) ? kt + 1 : kt;
      if (!(kt == 7 && m == 3)) {
#pragma unroll
        for (int i = 0; i < 8; ++i)
          avN[i] = wcb[(size_t)(ktn * 32 + lg * 8 + i) * kC + c0 + mn * 16 + lr];
      }
      bf16x8 ah, al;
#pragma unroll
      for (int i = 0; i < 8; ++i) {
        const ushort h = f2bf(avC[i]);
        ah[i] = (short)h;
        al[i] = (short)f2bf(avC[i] - bf2f(h));
      }
#pragma unroll
      for (int n = 0; n < 2; ++n) {
        acc[m][n] = MFMA16(ah, bh[n], acc[m][n]);
        acc[m][n] = MFMA16(ah, bl[n], acc[m][n]);
        acc[m][n] = MFMA16(al, bh[n], acc[m][n]);
      }
#pragma unroll
      for (int i = 0; i < 8; ++i) avC[i] = avN[i];
    }
  }

  // ---- softmax over s (row c = c0+m*16+lg*4+j; cols s=lr, 16+lr) ----
  float* attnb = attn_out + ((size_t)b * kC + cb) * kS;
#pragma unroll
  for (int m = 0; m < 4; ++m) {
#pragma unroll
    for (int j = 0; j < 4; ++j) {
      float v0 = acc[m][0][j], v1 = acc[m][1][j];
      float mx = fmaxf(v0, v1);
      mx = fmaxf(mx, __shfl_xor(mx, 1));
      mx = fmaxf(mx, __shfl_xor(mx, 2));
      mx = fmaxf(mx, __shfl_xor(mx, 4));
      mx = fmaxf(mx, __shfl_xor(mx, 8));
      float e0 = __expf(v0 - mx), e1 = __expf(v1 - mx);
      float sm = e0 + e1;
      sm += __shfl_xor(sm, 1); sm += __shfl_xor(sm, 2);
      sm += __shfl_xor(sm, 4); sm += __shfl_xor(sm, 8);
      const float inv = 1.f / sm;
      e0 *= inv; e1 *= inv;
      const int cL = wave * 64 + m * 16 + lg * 4 + j;
      attnb[(size_t)cL * kS + lr]      = e0;
      attnb[(size_t)cL * kS + 16 + lr] = e1;
      pHl[cL][lr]      = f2bf(e0);
      pHl[cL][16 + lr] = f2bf(e1);
    }
  }
  // P rows are wave-local: no barrier needed.

  // ---- Phase B: D[p][c] = weT(hi, LDS) x P(hi, LDS), K=32 ----
  bf16x8 pbh[4];
#pragma unroll
  for (int n = 0; n < 4; ++n)
    pbh[n] = *(const bf16x8*)&pHl[wave * 64 + n * 16 + lr][lg * 8];

  float* outb = out + (size_t)b * kHW * kC + cb;
#pragma unroll 1
  for (int pt = 0; pt < 16; ++pt) {
    const bf16x8 ah = *(const bf16x8*)&wHp[pt * 16 + lr][lg * 8];
#pragma unroll
    for (int n = 0; n < 4; ++n) {
      f32x4 o = (f32x4){0.f, 0.f, 0.f, 0.f};
      o = MFMA16(ah, pbh[n], o);
      const int ccol = wave * 64 + n * 16 + lr;
#pragma unroll
      for (int j = 0; j < 4; ++j)
        outb[(size_t)(pt * 16 + lg * 4 + j) * kC + ccol] = o[j];
    }
  }
}

extern "C" void kernel_launch(void* const* d_in, const int* in_sizes, int n_in,
                              void* d_out, int out_size, void* d_ws, size_t ws_size,
                              hipStream_t stream) {
  const float* wc   = (const float*)d_in[0];
  const float* emb  = (const float*)d_in[1];
  const float* Km   = (const float*)d_in[2];
  const float* bias = (const float*)d_in[3];

  float* out  = (float*)d_out;
  float* attn = out + (size_t)kB * kHW * kC;

  fused_attn_kernel<<<dim3(4, kB), 256, 0, stream>>>(wc, emb, Km, bias, out, attn);
}